// Round 3
// baseline (52.575 us; speedup 1.0000x reference)
//
#include <hip/hip_runtime.h>
#include <stdint.h>

// ChunkMasker: mask is input-independent (jax.random.key(1)), bit-exact
// (absmax 0) since R0 with jax_threefry_partitionable semantics.
// R1: fused RNG+scan (chunk-union + binary search), mask-skipped reads.
// R2: frame-per-block apply — one block per (b,t) frame, 192 threads = 3
// waves = 768 floats. Mask predicate is block-uniform (s_cbranch, no lane
// divergence), no per-thread flat-index division on the hot path.

#define B_ 32
#define T_ 1500
#define D_ 768
#define G_ 1500            // guard budget = 4 * num_to_mask
#define NUM_TO_MASK 375
#define NWORDS 47          // ceil(1500/32)
#define NCHUNK ((G_ + 63) / 64)
#define NX (B_*T_*D_)      // 36864000
#define NMASK (B_*T_)      // 48000
#define NMASK4 (NMASK/4)   // 12000
#define NFRAME (B_*T_)     // 48000 frame blocks
#define NTAILB 63          // ceil(12000/192) tail blocks

typedef float f4 __attribute__((ext_vector_type(4)));

__host__ __device__ static inline void tf2x32(uint32_t ka, uint32_t kb,
                                              uint32_t x0, uint32_t x1,
                                              uint32_t &o0, uint32_t &o1) {
  uint32_t kc = ka ^ kb ^ 0x1BD11BDAu;
#define TFR(r) { x0 += x1; x1 = ((x1 << (r)) | (x1 >> (32 - (r)))); x1 ^= x0; }
  x0 += ka; x1 += kb;
  TFR(13) TFR(15) TFR(26) TFR(6)   x0 += kb; x1 += kc + 1u;
  TFR(17) TFR(29) TFR(16) TFR(24)  x0 += kc; x1 += ka + 2u;
  TFR(13) TFR(15) TFR(26) TFR(6)   x0 += ka; x1 += kb + 3u;
  TFR(17) TFR(29) TFR(16) TFR(24)  x0 += kb; x1 += kc + 4u;
  TFR(13) TFR(15) TFR(26) TFR(6)   x0 += kc; x1 += ka + 5u;
#undef TFR
  o0 = x0; o1 = x1;
}

__device__ static inline int wave_sum64(int v) {
  for (int s = 1; s < 64; s <<= 1) v += __shfl_xor(v, s);
  return v;
}

// One block (one wave) per batch element. Fused RNG + order-independent scan
// (verified bit-exact R1). Chunk-union trial via LDS atomicOr; binary search
// for the crossing attempt inside the crossing chunk.
__global__ void __launch_bounds__(64)
scan_kernel(uint32_t* __restrict__ bits,
            uint32_t k1b0, uint32_t k1b1,
            uint32_t k2a0, uint32_t k2a1,
            uint32_t k2b0, uint32_t k2b1) {
  const int b = blockIdx.x;
  const int l = threadIdx.x;
  __shared__ uint32_t u[NWORDS];   // committed union
  __shared__ uint32_t t[NWORDS];   // trial union
  if (l < NWORDS) u[l] = 0u;
  __syncthreads();
  bool done = false;
  for (int chunk = 0; chunk < NCHUNK && !done; ++chunk) {
    const int g = chunk * 64 + l;
    const bool valid = (g < G_);
    uint32_t m0 = 0u, m1 = 0u;
    int w0 = 0, w1 = 0;
    if (valid) {
      const uint32_t f = (uint32_t)(g * B_ + b);
      uint32_t a0, a1;
      tf2x32(k1b0, k1b1, 0u, f, a0, a1);
      const uint32_t len = 2u + ((a0 ^ a1) & 3u);      // randint [2,6)
      tf2x32(k2a0, k2a1, 0u, f, a0, a1);
      const uint32_t hb = a0 ^ a1;
      tf2x32(k2b0, k2b1, 0u, f, a0, a1);
      const uint32_t lb = a0 ^ a1;
      const uint32_t span = (uint32_t)T_ - len;
      uint32_t mm = 65536u % span;
      mm = (mm * mm) % span;
      const uint32_t start = ((hb % span) * mm + (lb % span)) % span;
      const uint32_t end = start + len;                // <= 1500
      w0 = (int)(start >> 5);
      w1 = (int)((end - 1u) >> 5);
      const int sh = (int)(start & 31u);
      const int n0 = min((int)len, 32 - sh);           // 1..5
      m0 = ((1u << n0) - 1u) << sh;
      if (w1 != w0) m1 = (1u << ((int)len - n0)) - 1u;
    }
    if (l < NWORDS) t[l] = u[l];
    __syncthreads();
    if (valid) { atomicOr(&t[w0], m0); if (w1 != w0) atomicOr(&t[w1], m1); }
    __syncthreads();
    int tot = wave_sum64((l < NWORDS) ? __popc(t[l]) : 0);
    if (tot < NUM_TO_MASK) {
      __syncthreads();
      if (l < NWORDS) u[l] = t[l];
      __syncthreads();
      continue;
    }
    int lo = 0;
    int hi = min(63, G_ - chunk * 64 - 1);
    while (lo < hi) {
      const int mid = (lo + hi) >> 1;
      __syncthreads();
      if (l < NWORDS) t[l] = u[l];
      __syncthreads();
      if (valid && l <= mid) { atomicOr(&t[w0], m0); if (w1 != w0) atomicOr(&t[w1], m1); }
      __syncthreads();
      tot = wave_sum64((l < NWORDS) ? __popc(t[l]) : 0);
      if (tot >= NUM_TO_MASK) hi = mid; else lo = mid + 1;
    }
    __syncthreads();
    if (l < NWORDS) t[l] = u[l];
    __syncthreads();
    if (valid && l <= lo) { atomicOr(&t[w0], m0); if (w1 != w0) atomicOr(&t[w1], m1); }
    __syncthreads();
    if (l < NWORDS) u[l] = t[l];
    done = true;
  }
  __syncthreads();
  if (l < NWORDS) bits[b * NWORDS + l] = u[l];
}

// Frame-per-block apply. Block bt < 48000: copy-or-zero one 768-float frame
// (192 threads x float4). Predicate is block-uniform -> s_cbranch, masked
// frames never touch x. Blocks >= 48000: float mask tail.
__global__ void __launch_bounds__(192)
apply_kernel(const f4* __restrict__ x4, f4* __restrict__ out4,
             const uint32_t* __restrict__ bits) {
  const int blk = blockIdx.x;
  const int tid = threadIdx.x;
  if (blk < NFRAME) {
    const int b = blk / T_;                   // scalar magic-mul
    const int t = blk - b * T_;
    const uint32_t w = bits[b * NWORDS + (t >> 5)];   // block-uniform
    const int idx = blk * (D_ / 4) + tid;     // 192 f4 per frame
    f4 v = (f4)(0.f);
    if (!((w >> (t & 31)) & 1u)) v = __builtin_nontemporal_load(&x4[idx]);
    __builtin_nontemporal_store(v, &out4[idx]);
  } else {
    const int i = (blk - NFRAME) * 192 + tid; // tail float4 index
    if (i < NMASK4) {
      const int f0 = i * 4;                   // b*1500 + t0, t0 % 4 == 0
      const int b = f0 / T_;
      const int t0 = f0 - b * T_;
      const uint32_t w = bits[b * NWORDS + (t0 >> 5)];  // t0&31 <= 28
      f4 v;
      v.x = ((w >> ((t0 + 0) & 31)) & 1u) ? 1.f : 0.f;
      v.y = ((w >> ((t0 + 1) & 31)) & 1u) ? 1.f : 0.f;
      v.z = ((w >> ((t0 + 2) & 31)) & 1u) ? 1.f : 0.f;
      v.w = ((w >> ((t0 + 3) & 31)) & 1u) ? 1.f : 0.f;
      __builtin_nontemporal_store(v, &out4[(size_t)(NX / 4) + i]);
    }
  }
}

extern "C" void kernel_launch(void* const* d_in, const int* in_sizes, int n_in,
                              void* d_out, int out_size, void* d_ws, size_t ws_size,
                              hipStream_t stream) {
  const float* x = (const float*)d_in[0];
  float* out = (float*)d_out;
  uint32_t* bits = (uint32_t*)d_ws;           // 6016 B

  // Host-side key derivation (partitionable fold-like split), verified R0:
  // root = key(1) = (0,1); k1 = cipher(root,(0,0)), k2 = cipher(root,(0,1))
  // lens  : k1b = cipher(k1,(0,1))   (k1a unused: span=4 -> multiplier 0)
  // starts: k2a = cipher(k2,(0,0)), k2b = cipher(k2,(0,1))
  uint32_t k1_0, k1_1, k2_0, k2_1;
  tf2x32(0u, 1u, 0u, 0u, k1_0, k1_1);
  tf2x32(0u, 1u, 0u, 1u, k2_0, k2_1);
  uint32_t k1b0, k1b1, k2a0, k2a1, k2b0, k2b1;
  tf2x32(k1_0, k1_1, 0u, 1u, k1b0, k1b1);
  tf2x32(k2_0, k2_1, 0u, 0u, k2a0, k2a1);
  tf2x32(k2_0, k2_1, 0u, 1u, k2b0, k2b1);

  hipLaunchKernelGGL(scan_kernel, dim3(B_), dim3(64), 0, stream,
                     bits, k1b0, k1b1, k2a0, k2a1, k2b0, k2b1);
  hipLaunchKernelGGL(apply_kernel, dim3(NFRAME + NTAILB), dim3(192), 0, stream,
                     (const f4*)x, (f4*)out, bits);
}

// Round 4
// 46.528 us; speedup vs baseline: 1.1300x; 1.1300x over previous
//
#include <hip/hip_runtime.h>
#include <stdint.h>

// ChunkMasker: mask is input-independent (jax.random.key(1)), bit-exact
// (absmax 0) since R0 with jax_threefry_partitionable semantics.
// R1: fused RNG+scan (chunk-union + binary search), mask-skipped reads.
// R2: frame-per-block apply (block-uniform predicate) — neutral.
// R3: drop nontemporal hint on x loads. x (147 MB) fits in the 256 MB
// Infinity Cache and is re-read every graph replay; NT loads forced those
// reads to HBM each replay. NT stores stay (out is write-once streaming,
// keeping it out of LLC leaves the whole LLC for x).

#define B_ 32
#define T_ 1500
#define D_ 768
#define G_ 1500            // guard budget = 4 * num_to_mask
#define NUM_TO_MASK 375
#define NWORDS 47          // ceil(1500/32)
#define NCHUNK ((G_ + 63) / 64)
#define NX (B_*T_*D_)      // 36864000
#define NMASK (B_*T_)      // 48000
#define NMASK4 (NMASK/4)   // 12000
#define NFRAME (B_*T_)     // 48000 frame blocks
#define NTAILB 63          // ceil(12000/192) tail blocks

typedef float f4 __attribute__((ext_vector_type(4)));

__host__ __device__ static inline void tf2x32(uint32_t ka, uint32_t kb,
                                              uint32_t x0, uint32_t x1,
                                              uint32_t &o0, uint32_t &o1) {
  uint32_t kc = ka ^ kb ^ 0x1BD11BDAu;
#define TFR(r) { x0 += x1; x1 = ((x1 << (r)) | (x1 >> (32 - (r)))); x1 ^= x0; }
  x0 += ka; x1 += kb;
  TFR(13) TFR(15) TFR(26) TFR(6)   x0 += kb; x1 += kc + 1u;
  TFR(17) TFR(29) TFR(16) TFR(24)  x0 += kc; x1 += ka + 2u;
  TFR(13) TFR(15) TFR(26) TFR(6)   x0 += ka; x1 += kb + 3u;
  TFR(17) TFR(29) TFR(16) TFR(24)  x0 += kb; x1 += kc + 4u;
  TFR(13) TFR(15) TFR(26) TFR(6)   x0 += kc; x1 += ka + 5u;
#undef TFR
  o0 = x0; o1 = x1;
}

__device__ static inline int wave_sum64(int v) {
  for (int s = 1; s < 64; s <<= 1) v += __shfl_xor(v, s);
  return v;
}

// One block (one wave) per batch element. Fused RNG + order-independent scan
// (verified bit-exact R1). Chunk-union trial via LDS atomicOr; binary search
// for the crossing attempt inside the crossing chunk.
__global__ void __launch_bounds__(64)
scan_kernel(uint32_t* __restrict__ bits,
            uint32_t k1b0, uint32_t k1b1,
            uint32_t k2a0, uint32_t k2a1,
            uint32_t k2b0, uint32_t k2b1) {
  const int b = blockIdx.x;
  const int l = threadIdx.x;
  __shared__ uint32_t u[NWORDS];   // committed union
  __shared__ uint32_t t[NWORDS];   // trial union
  if (l < NWORDS) u[l] = 0u;
  __syncthreads();
  bool done = false;
  for (int chunk = 0; chunk < NCHUNK && !done; ++chunk) {
    const int g = chunk * 64 + l;
    const bool valid = (g < G_);
    uint32_t m0 = 0u, m1 = 0u;
    int w0 = 0, w1 = 0;
    if (valid) {
      const uint32_t f = (uint32_t)(g * B_ + b);
      uint32_t a0, a1;
      tf2x32(k1b0, k1b1, 0u, f, a0, a1);
      const uint32_t len = 2u + ((a0 ^ a1) & 3u);      // randint [2,6)
      tf2x32(k2a0, k2a1, 0u, f, a0, a1);
      const uint32_t hb = a0 ^ a1;
      tf2x32(k2b0, k2b1, 0u, f, a0, a1);
      const uint32_t lb = a0 ^ a1;
      const uint32_t span = (uint32_t)T_ - len;
      uint32_t mm = 65536u % span;
      mm = (mm * mm) % span;
      const uint32_t start = ((hb % span) * mm + (lb % span)) % span;
      const uint32_t end = start + len;                // <= 1500
      w0 = (int)(start >> 5);
      w1 = (int)((end - 1u) >> 5);
      const int sh = (int)(start & 31u);
      const int n0 = min((int)len, 32 - sh);           // 1..5
      m0 = ((1u << n0) - 1u) << sh;
      if (w1 != w0) m1 = (1u << ((int)len - n0)) - 1u;
    }
    if (l < NWORDS) t[l] = u[l];
    __syncthreads();
    if (valid) { atomicOr(&t[w0], m0); if (w1 != w0) atomicOr(&t[w1], m1); }
    __syncthreads();
    int tot = wave_sum64((l < NWORDS) ? __popc(t[l]) : 0);
    if (tot < NUM_TO_MASK) {
      __syncthreads();
      if (l < NWORDS) u[l] = t[l];
      __syncthreads();
      continue;
    }
    int lo = 0;
    int hi = min(63, G_ - chunk * 64 - 1);
    while (lo < hi) {
      const int mid = (lo + hi) >> 1;
      __syncthreads();
      if (l < NWORDS) t[l] = u[l];
      __syncthreads();
      if (valid && l <= mid) { atomicOr(&t[w0], m0); if (w1 != w0) atomicOr(&t[w1], m1); }
      __syncthreads();
      tot = wave_sum64((l < NWORDS) ? __popc(t[l]) : 0);
      if (tot >= NUM_TO_MASK) hi = mid; else lo = mid + 1;
    }
    __syncthreads();
    if (l < NWORDS) t[l] = u[l];
    __syncthreads();
    if (valid && l <= lo) { atomicOr(&t[w0], m0); if (w1 != w0) atomicOr(&t[w1], m1); }
    __syncthreads();
    if (l < NWORDS) u[l] = t[l];
    done = true;
  }
  __syncthreads();
  if (l < NWORDS) bits[b * NWORDS + l] = u[l];
}

// Frame-per-block apply. Block bt < 48000: copy-or-zero one 768-float frame
// (192 threads x float4). Predicate is block-uniform -> s_cbranch, masked
// frames never touch x. Blocks >= 48000: float mask tail.
// x loads CACHED (LLC-resident across replays); out stores nontemporal.
__global__ void __launch_bounds__(192)
apply_kernel(const f4* __restrict__ x4, f4* __restrict__ out4,
             const uint32_t* __restrict__ bits) {
  const int blk = blockIdx.x;
  const int tid = threadIdx.x;
  if (blk < NFRAME) {
    const int b = blk / T_;                   // scalar magic-mul
    const int t = blk - b * T_;
    const uint32_t w = bits[b * NWORDS + (t >> 5)];   // block-uniform
    const int idx = blk * (D_ / 4) + tid;     // 192 f4 per frame
    f4 v = (f4)(0.f);
    if (!((w >> (t & 31)) & 1u)) v = x4[idx];         // cached load
    __builtin_nontemporal_store(v, &out4[idx]);
  } else {
    const int i = (blk - NFRAME) * 192 + tid; // tail float4 index
    if (i < NMASK4) {
      const int f0 = i * 4;                   // b*1500 + t0, t0 % 4 == 0
      const int b = f0 / T_;
      const int t0 = f0 - b * T_;
      const uint32_t w = bits[b * NWORDS + (t0 >> 5)];  // t0&31 <= 28
      f4 v;
      v.x = ((w >> ((t0 + 0) & 31)) & 1u) ? 1.f : 0.f;
      v.y = ((w >> ((t0 + 1) & 31)) & 1u) ? 1.f : 0.f;
      v.z = ((w >> ((t0 + 2) & 31)) & 1u) ? 1.f : 0.f;
      v.w = ((w >> ((t0 + 3) & 31)) & 1u) ? 1.f : 0.f;
      __builtin_nontemporal_store(v, &out4[(size_t)(NX / 4) + i]);
    }
  }
}

extern "C" void kernel_launch(void* const* d_in, const int* in_sizes, int n_in,
                              void* d_out, int out_size, void* d_ws, size_t ws_size,
                              hipStream_t stream) {
  const float* x = (const float*)d_in[0];
  float* out = (float*)d_out;
  uint32_t* bits = (uint32_t*)d_ws;           // 6016 B

  // Host-side key derivation (partitionable fold-like split), verified R0:
  // root = key(1) = (0,1); k1 = cipher(root,(0,0)), k2 = cipher(root,(0,1))
  // lens  : k1b = cipher(k1,(0,1))   (k1a unused: span=4 -> multiplier 0)
  // starts: k2a = cipher(k2,(0,0)), k2b = cipher(k2,(0,1))
  uint32_t k1_0, k1_1, k2_0, k2_1;
  tf2x32(0u, 1u, 0u, 0u, k1_0, k1_1);
  tf2x32(0u, 1u, 0u, 1u, k2_0, k2_1);
  uint32_t k1b0, k1b1, k2a0, k2a1, k2b0, k2b1;
  tf2x32(k1_0, k1_1, 0u, 1u, k1b0, k1b1);
  tf2x32(k2_0, k2_1, 0u, 0u, k2a0, k2a1);
  tf2x32(k2_0, k2_1, 0u, 1u, k2b0, k2b1);

  hipLaunchKernelGGL(scan_kernel, dim3(B_), dim3(64), 0, stream,
                     bits, k1b0, k1b1, k2a0, k2a1, k2b0, k2b1);
  hipLaunchKernelGGL(apply_kernel, dim3(NFRAME + NTAILB), dim3(192), 0, stream,
                     (const f4*)x, (f4*)out, bits);
}